// Round 1
// baseline (59.498 us; speedup 1.0000x reference)
//
#include <hip/hip_runtime.h>

// Problem constants (from reference): x (B=64, C_in=8, L=65536) fp32,
// W (C_out=8, C_in=8, FS=4), b (8,), circular padding by FS-1=3, stride 1.
#define BATCH 64
#define CIN 8
#define COUT 8
#define LEN 65536
#define FS 4
#define TILE 1024          // positions per block (256 threads x 4)

__global__ __launch_bounds__(256) void conv_pbc_kernel(
    const float* __restrict__ x,
    const float* __restrict__ W,
    const float* __restrict__ bias,
    float* __restrict__ out)
{
    __shared__ float sW[COUT * CIN * FS];   // 256 floats
    __shared__ float sB[COUT];

    const int tid = threadIdx.x;
    if (tid < COUT * CIN * FS) sW[tid] = W[tid];
    if (tid < COUT)            sB[tid] = bias[tid];
    __syncthreads();

    const int blocksPerBatch = LEN / TILE;              // 64
    const int b    = blockIdx.x / blocksPerBatch;
    const int tile = blockIdx.x % blocksPerBatch;
    const int l0   = tile * TILE + tid * 4;             // first output position

    const float* xb = x + (size_t)b * CIN * LEN;

    float acc[COUT][4];
#pragma unroll
    for (int co = 0; co < COUT; ++co) {
        const float bb = sB[co];
        acc[co][0] = bb; acc[co][1] = bb; acc[co][2] = bb; acc[co][3] = bb;
    }

    // Need x[l0 .. l0+6]; we load two aligned float4 (l0..l0+7).
    const bool fast = (l0 + 8 <= LEN);

#pragma unroll
    for (int ci = 0; ci < CIN; ++ci) {
        const float* xc = xb + (size_t)ci * LEN;
        float xv[8];
        if (fast) {
            const float4 v0 = *reinterpret_cast<const float4*>(xc + l0);
            const float4 v1 = *reinterpret_cast<const float4*>(xc + l0 + 4);
            xv[0] = v0.x; xv[1] = v0.y; xv[2] = v0.z; xv[3] = v0.w;
            xv[4] = v1.x; xv[5] = v1.y; xv[6] = v1.z; xv[7] = v1.w;
        } else {
            // circular wrap; LEN is a power of two
#pragma unroll
            for (int j = 0; j < 8; ++j)
                xv[j] = xc[(l0 + j) & (LEN - 1)];
        }

#pragma unroll
        for (int co = 0; co < COUT; ++co) {
#pragma unroll
            for (int k = 0; k < FS; ++k) {
                const float w = sW[(co * CIN + ci) * FS + k];  // wave-uniform broadcast
#pragma unroll
                for (int p = 0; p < 4; ++p)
                    acc[co][p] += w * xv[p + k];
            }
        }
    }

    float* ob = out + (size_t)b * COUT * LEN + l0;
#pragma unroll
    for (int co = 0; co < COUT; ++co) {
        float4 v;
        v.x = acc[co][0]; v.y = acc[co][1]; v.z = acc[co][2]; v.w = acc[co][3];
        *reinterpret_cast<float4*>(ob + (size_t)co * LEN) = v;
    }
}

extern "C" void kernel_launch(void* const* d_in, const int* in_sizes, int n_in,
                              void* d_out, int out_size, void* d_ws, size_t ws_size,
                              hipStream_t stream) {
    const float* x    = (const float*)d_in[0];
    const float* W    = (const float*)d_in[1];
    const float* bias = (const float*)d_in[2];
    float* out = (float*)d_out;

    const int blocksPerBatch = LEN / TILE;            // 64
    const dim3 grid(BATCH * blocksPerBatch);          // 4096 blocks
    const dim3 block(256);
    conv_pbc_kernel<<<grid, block, 0, stream>>>(x, W, bias, out);
}

// Round 2
// 50.237 us; speedup vs baseline: 1.1844x; 1.1844x over previous
//
#include <hip/hip_runtime.h>

// Circular conv1d: x (B=64, C_in=8, L=65536) fp32, W (8,8,4), b (8,),
// circular pad by FS-1=3, stride 1. Memory-bound; goal = hide load latency.
#define BATCH 64
#define CIN 8
#define COUT 8
#define LEN 65536
#define FS 4
#define TILE 1024          // positions per block (256 threads x 4)

// __launch_bounds__(256, 4): 4 waves/SIMD min -> caps VGPR at 128.
// R1 had 156 VGPR (full-unroll kept 64 xv floats live) -> 2 waves/SIMD,
// occupancy 9.6%, latency-bound. Partial unroll keeps only 2 channels of
// xv live; TLP (16 waves/CU) hides global-load latency instead of ILP.
__global__ __launch_bounds__(256, 4) void conv_pbc_kernel(
    const float* __restrict__ x,
    const float* __restrict__ W,
    const float* __restrict__ bias,
    float* __restrict__ out)
{
    __shared__ float sW[COUT * CIN * FS];   // 256 floats
    __shared__ float sB[COUT];

    const int tid = threadIdx.x;
    if (tid < COUT * CIN * FS) sW[tid] = W[tid];
    if (tid < COUT)            sB[tid] = bias[tid];
    __syncthreads();

    const int blocksPerBatch = LEN / TILE;              // 64
    const int b    = blockIdx.x / blocksPerBatch;
    const int tile = blockIdx.x % blocksPerBatch;
    const int l0   = tile * TILE + tid * 4;             // first output position

    const float* xb = x + (size_t)b * CIN * LEN;

    float acc[COUT][4];
#pragma unroll
    for (int co = 0; co < COUT; ++co) {
        const float bb = sB[co];
        acc[co][0] = bb; acc[co][1] = bb; acc[co][2] = bb; acc[co][3] = bb;
    }

    // Need x[l0 .. l0+6]; load two aligned float4 (l0..l0+7).
    const bool fast = (l0 + 8 <= LEN);

#pragma unroll 2
    for (int ci = 0; ci < CIN; ++ci) {
        const float* xc = xb + (size_t)ci * LEN;
        float xv[8];
        if (fast) {
            const float4 v0 = *reinterpret_cast<const float4*>(xc + l0);
            const float4 v1 = *reinterpret_cast<const float4*>(xc + l0 + 4);
            xv[0] = v0.x; xv[1] = v0.y; xv[2] = v0.z; xv[3] = v0.w;
            xv[4] = v1.x; xv[5] = v1.y; xv[6] = v1.z; xv[7] = v1.w;
        } else {
            // circular wrap; LEN is a power of two (only last thread per batch)
#pragma unroll
            for (int j = 0; j < 8; ++j)
                xv[j] = xc[(l0 + j) & (LEN - 1)];
        }

#pragma unroll
        for (int co = 0; co < COUT; ++co) {
#pragma unroll
            for (int k = 0; k < FS; ++k) {
                const float w = sW[(co * CIN + ci) * FS + k];  // wave-uniform broadcast
#pragma unroll
                for (int p = 0; p < 4; ++p)
                    acc[co][p] += w * xv[p + k];
            }
        }
    }

    float* ob = out + (size_t)b * COUT * LEN + l0;
#pragma unroll
    for (int co = 0; co < COUT; ++co) {
        float4 v;
        v.x = acc[co][0]; v.y = acc[co][1]; v.z = acc[co][2]; v.w = acc[co][3];
        *reinterpret_cast<float4*>(ob + (size_t)co * LEN) = v;
    }
}

extern "C" void kernel_launch(void* const* d_in, const int* in_sizes, int n_in,
                              void* d_out, int out_size, void* d_ws, size_t ws_size,
                              hipStream_t stream) {
    const float* x    = (const float*)d_in[0];
    const float* W    = (const float*)d_in[1];
    const float* bias = (const float*)d_in[2];
    float* out = (float*)d_out;

    const int blocksPerBatch = LEN / TILE;            // 64
    const dim3 grid(BATCH * blocksPerBatch);          // 4096 blocks
    const dim3 block(256);
    conv_pbc_kernel<<<grid, block, 0, stream>>>(x, W, bias, out);
}